// Round 1
// baseline (4304.946 us; speedup 1.0000x reference)
//
#include <hip/hip_runtime.h>

#define D_ 512
#define H_ 8
#define HD_ 64
#define B_ 2
#define S_ 12
#define N_ 512
#define BS_ 24            // B*S
#define M_ 192            // H*B*S
#define T_ 12288          // B*S*N
#define PROJ_ELEMS (M_ * N_ * HD_)   // 6291456 floats = 25.2 MB

struct ProjArgs {
    const float* src[7];
    const float* w[7];
    const float* b[7];
    float* dst[7];
};

// out[token, dcol] = sum_k A[token,k]*W[k,dcol] + b[dcol], stored split-head:
// h = dcol>>6, hd = dcol&63, m = h*24 + (token>>9), n = token&511
// -> dst[((m*512 + n)<<6) + hd]
__global__ __launch_bounds__(256) void proj_kernel(ProjArgs args) {
    const int z = blockIdx.z;
    const float* __restrict__ A = args.src[z];
    const float* __restrict__ W = args.w[z];
    const float* __restrict__ bias = args.b[z];
    float* __restrict__ O = args.dst[z];

    __shared__ float AsT[32][68];   // [k][row], padded stride for b128 alignment
    __shared__ float Bs[32][68];    // [k][col]

    const int tid = threadIdx.x;
    const int tx = tid & 15;
    const int ty = tid >> 4;
    const int row0 = blockIdx.x * 64;
    const int col0 = blockIdx.y * 64;

    float acc[4][4] = {};

    for (int k0 = 0; k0 < 512; k0 += 32) {
        {
            const int r = tid >> 2;               // 0..63
            const int c0 = (tid & 3) * 8;         // 0,8,16,24
            const float* src = &A[(size_t)(row0 + r) * 512 + k0 + c0];
            float4 v0 = *(const float4*)(src);
            float4 v1 = *(const float4*)(src + 4);
            AsT[c0 + 0][r] = v0.x; AsT[c0 + 1][r] = v0.y;
            AsT[c0 + 2][r] = v0.z; AsT[c0 + 3][r] = v0.w;
            AsT[c0 + 4][r] = v1.x; AsT[c0 + 5][r] = v1.y;
            AsT[c0 + 6][r] = v1.z; AsT[c0 + 7][r] = v1.w;

            const int rb = tid >> 3;              // 0..31
            const int cb = (tid & 7) * 8;         // 0..56
            const float* srcB = &W[(size_t)(k0 + rb) * 512 + col0 + cb];
            float4 w0 = *(const float4*)(srcB);
            float4 w1 = *(const float4*)(srcB + 4);
            *(float4*)&Bs[rb][cb] = w0;
            *(float4*)&Bs[rb][cb + 4] = w1;
        }
        __syncthreads();
        #pragma unroll
        for (int kk = 0; kk < 32; ++kk) {
            float4 a4 = *(const float4*)&AsT[kk][ty * 4];
            float4 b4 = *(const float4*)&Bs[kk][tx * 4];
            float av[4] = {a4.x, a4.y, a4.z, a4.w};
            float bv[4] = {b4.x, b4.y, b4.z, b4.w};
            #pragma unroll
            for (int r = 0; r < 4; ++r)
                #pragma unroll
                for (int c = 0; c < 4; ++c)
                    acc[r][c] += av[r] * bv[c];
        }
        __syncthreads();
    }

    #pragma unroll
    for (int r = 0; r < 4; ++r) {
        const int trow = row0 + ty * 4 + r;
        const int bs = trow >> 9;
        const int n = trow & 511;
        #pragma unroll
        for (int c = 0; c < 4; ++c) {
            const int dcol = col0 + tx * 4 + c;
            const int h = dcol >> 6;
            const int hd = dcol & 63;
            const int m = h * BS_ + bs;
            O[((size_t)(m * 512 + n) << 6) + hd] = acc[r][c] + bias[dcol];
        }
    }
}

// Fused masking + attention per (m, 16-row block). 4 waves x 4 rows.
__global__ __launch_bounds__(256) void attn_kernel(
    const float* __restrict__ gq, const float* __restrict__ gk,
    const float* __restrict__ gv, const float* __restrict__ lq,
    const float* __restrict__ lk, const float* __restrict__ mq,
    const float* __restrict__ mk, float* __restrict__ aout)
{
    __shared__ float mqs[16][64];
    __shared__ float gqs[16][64];
    __shared__ float lqs[16][64];
    __shared__ float tA[64][64];    // [d][j] transposed K tiles / [j][d] V tile
    __shared__ float tB[64][64];    // [d][j] for lk
    __shared__ float ps[16][512];   // softmax probs per row

    const int m = blockIdx.x;           // 0..191
    const int i0 = blockIdx.y * 16;     // row block start
    const int tid = threadIdx.x;
    const int wave = tid >> 6;
    const int lane = tid & 63;
    const size_t base = (size_t)m * (512 * 64);

    {
        const int idx = tid * 4;
        const int r = idx >> 6;
        const int d = idx & 63;
        const size_t off = base + (size_t)(i0 + r) * 64 + d;
        *(float4*)&mqs[r][d] = *(const float4*)&mq[off];
        *(float4*)&gqs[r][d] = *(const float4*)&gq[off];
        *(float4*)&lqs[r][d] = *(const float4*)&lq[off];
    }
    __syncthreads();

    float att[4][8];   // att[r][jt]: j = jt*64 + lane

    // ---- Pass 1: masking attention scores (mq . mk^T, unscaled) ----
    for (int jt = 0; jt < 8; ++jt) {
        {
            const int j = tid & 63;
            const int d0 = (tid >> 6) * 16;
            const size_t src = base + (size_t)(jt * 64 + j) * 64 + d0;
            #pragma unroll
            for (int dd = 0; dd < 16; dd += 4) {
                float4 v4 = *(const float4*)&mk[src + dd];
                tA[d0 + dd + 0][j] = v4.x;
                tA[d0 + dd + 1][j] = v4.y;
                tA[d0 + dd + 2][j] = v4.z;
                tA[d0 + dd + 3][j] = v4.w;
            }
        }
        __syncthreads();
        {
            float a0 = 0.f, a1 = 0.f, a2 = 0.f, a3 = 0.f;
            #pragma unroll
            for (int d = 0; d < 64; ++d) {
                const float kv = tA[d][lane];
                a0 += mqs[wave * 4 + 0][d] * kv;
                a1 += mqs[wave * 4 + 1][d] * kv;
                a2 += mqs[wave * 4 + 2][d] * kv;
                a3 += mqs[wave * 4 + 3][d] * kv;
            }
            att[0][jt] = a0; att[1][jt] = a1; att[2][jt] = a2; att[3][jt] = a3;
        }
        __syncthreads();
    }

    // ---- Row stats: argmax (first occurrence), sum|j-k| (closed form), mean_v ----
    int kidx[4];
    float sdv[4], mnv[4];
    #pragma unroll
    for (int r = 0; r < 4; ++r) {
        float mx = att[r][0];
        int mi = lane;
        #pragma unroll
        for (int jt = 1; jt < 8; ++jt) {
            const float v = att[r][jt];
            if (v > mx) { mx = v; mi = jt * 64 + lane; }
        }
        #pragma unroll
        for (int off = 32; off >= 1; off >>= 1) {
            const float v2 = __shfl_xor(mx, off, 64);
            const int i2 = __shfl_xor(mi, off, 64);
            if (v2 > mx || (v2 == mx && i2 < mi)) { mx = v2; mi = i2; }
        }
        const int kk = mi;
        // sum_j |j-k| over j=0..511 : exact integer, exact in fp32 (<2^24)
        const float sd = (float)(kk * (kk + 1) / 2 + (511 - kk) * (512 - kk) / 2);
        float part = 0.f;
        #pragma unroll
        for (int jt = 0; jt < 8; ++jt) {
            const int j = jt * 64 + lane;
            const float dis = fabsf((float)(j - kk)) / sd;
            part += fmaxf(att[r][jt], 0.f) * dis;
        }
        #pragma unroll
        for (int off = 32; off >= 1; off >>= 1) part += __shfl_xor(part, off, 64);
        kidx[r] = kk;
        sdv[r] = sd;
        mnv[r] = part * (1.f / 512.f);
    }

    // ---- Pass 2: gw, lw -> lambda -> causal logits (overwrite att regs) ----
    for (int jt = 0; jt < 8; ++jt) {
        {
            const int j = tid & 63;
            const int d0 = (tid >> 6) * 16;
            const size_t src = base + (size_t)(jt * 64 + j) * 64 + d0;
            #pragma unroll
            for (int dd = 0; dd < 16; dd += 4) {
                float4 vg = *(const float4*)&gk[src + dd];
                tA[d0 + dd + 0][j] = vg.x;
                tA[d0 + dd + 1][j] = vg.y;
                tA[d0 + dd + 2][j] = vg.z;
                tA[d0 + dd + 3][j] = vg.w;
                float4 vl = *(const float4*)&lk[src + dd];
                tB[d0 + dd + 0][j] = vl.x;
                tB[d0 + dd + 1][j] = vl.y;
                tB[d0 + dd + 2][j] = vl.z;
                tB[d0 + dd + 3][j] = vl.w;
            }
        }
        __syncthreads();
        {
            float g0=0.f,g1=0.f,g2=0.f,g3=0.f, l0=0.f,l1=0.f,l2=0.f,l3=0.f;
            #pragma unroll
            for (int d = 0; d < 64; ++d) {
                const float gkv = tA[d][lane];
                const float lkv = tB[d][lane];
                g0 += gqs[wave*4+0][d] * gkv;  l0 += lqs[wave*4+0][d] * lkv;
                g1 += gqs[wave*4+1][d] * gkv;  l1 += lqs[wave*4+1][d] * lkv;
                g2 += gqs[wave*4+2][d] * gkv;  l2 += lqs[wave*4+2][d] * lkv;
                g3 += gqs[wave*4+3][d] * gkv;  l3 += lqs[wave*4+3][d] * lkv;
            }
            const int j = jt * 64 + lane;
            float gg[4] = {g0, g1, g2, g3};
            float ll[4] = {l0, l1, l2, l3};
            #pragma unroll
            for (int r = 0; r < 4; ++r) {
                const int i = i0 + wave * 4 + r;
                const float dis = fabsf((float)(j - kidx[r])) / sdv[r];
                const float lam = (dis * att[r][jt] - mnv[r] >= 0.f) ? 1.f : 0.f;
                att[r][jt] = (j <= i)
                    ? (0.1f * (gg[r] * 0.125f) + (ll[r] * 0.125f) * lam)
                    : -__builtin_inff();
            }
        }
        __syncthreads();
    }

    // ---- Softmax per row (in register + wave reduces), write probs to LDS ----
    #pragma unroll
    for (int r = 0; r < 4; ++r) {
        const int row = wave * 4 + r;
        float mxl = att[r][0];
        #pragma unroll
        for (int jt = 1; jt < 8; ++jt) mxl = fmaxf(mxl, att[r][jt]);
        #pragma unroll
        for (int off = 32; off >= 1; off >>= 1) mxl = fmaxf(mxl, __shfl_xor(mxl, off, 64));
        float e[8];
        float sum = 0.f;
        #pragma unroll
        for (int jt = 0; jt < 8; ++jt) { e[jt] = expf(att[r][jt] - mxl); sum += e[jt]; }
        #pragma unroll
        for (int off = 32; off >= 1; off >>= 1) sum += __shfl_xor(sum, off, 64);
        const float inv = 1.f / sum;
        #pragma unroll
        for (int jt = 0; jt < 8; ++jt) ps[row][jt * 64 + lane] = e[jt] * inv;
    }

    // ---- Pass 3: PV (attn @ gv), d = lane ----
    float oacc[4] = {0.f, 0.f, 0.f, 0.f};
    for (int jt = 0; jt < 8; ++jt) {
        {
            const int jj = tid >> 2;              // 0..63
            const int d0 = (tid & 3) * 16;
            const size_t src = base + (size_t)(jt * 64 + jj) * 64 + d0;
            #pragma unroll
            for (int dd = 0; dd < 16; dd += 4)
                *(float4*)&tA[jj][d0 + dd] = *(const float4*)&gv[src + dd];
        }
        __syncthreads();
        #pragma unroll
        for (int jj = 0; jj < 64; ++jj) {
            const float gvv = tA[jj][lane];
            oacc[0] += ps[wave*4+0][jt*64+jj] * gvv;
            oacc[1] += ps[wave*4+1][jt*64+jj] * gvv;
            oacc[2] += ps[wave*4+2][jt*64+jj] * gvv;
            oacc[3] += ps[wave*4+3][jt*64+jj] * gvv;
        }
        __syncthreads();
    }
    #pragma unroll
    for (int r = 0; r < 4; ++r)
        aout[base + (size_t)(i0 + wave * 4 + r) * 64 + lane] = oacc[r];
}

// out[token, dcol] = sum_k X_perm[token, k]*W[k,dcol] + b[dcol]
// X_perm gathers attn_out: k -> (h=k>>6, hd=k&63), token -> (bs, n)
__global__ __launch_bounds__(256) void oproj_kernel(const float* __restrict__ X,
                                                    const float* __restrict__ W,
                                                    const float* __restrict__ bias,
                                                    float* __restrict__ Out) {
    __shared__ float AsT[32][68];
    __shared__ float Bs[32][68];

    const int tid = threadIdx.x;
    const int tx = tid & 15;
    const int ty = tid >> 4;
    const int row0 = blockIdx.x * 64;
    const int col0 = blockIdx.y * 64;

    float acc[4][4] = {};

    for (int k0 = 0; k0 < 512; k0 += 32) {
        const int h = k0 >> 6;
        const int hd0 = k0 & 63;   // 0 or 32
        {
            const int r = tid >> 2;
            const int c0 = (tid & 3) * 8;
            const int trow = row0 + r;
            const int bs = trow >> 9;
            const int n = trow & 511;
            const float* src = &X[(size_t)((h * BS_ + bs) * 512 + n) * 64 + hd0 + c0];
            float4 v0 = *(const float4*)(src);
            float4 v1 = *(const float4*)(src + 4);
            AsT[c0 + 0][r] = v0.x; AsT[c0 + 1][r] = v0.y;
            AsT[c0 + 2][r] = v0.z; AsT[c0 + 3][r] = v0.w;
            AsT[c0 + 4][r] = v1.x; AsT[c0 + 5][r] = v1.y;
            AsT[c0 + 6][r] = v1.z; AsT[c0 + 7][r] = v1.w;

            const int rb = tid >> 3;
            const int cb = (tid & 7) * 8;
            const float* srcB = &W[(size_t)(k0 + rb) * 512 + col0 + cb];
            float4 w0 = *(const float4*)(srcB);
            float4 w1 = *(const float4*)(srcB + 4);
            *(float4*)&Bs[rb][cb] = w0;
            *(float4*)&Bs[rb][cb + 4] = w1;
        }
        __syncthreads();
        #pragma unroll
        for (int kk = 0; kk < 32; ++kk) {
            float4 a4 = *(const float4*)&AsT[kk][ty * 4];
            float4 b4 = *(const float4*)&Bs[kk][tx * 4];
            float av[4] = {a4.x, a4.y, a4.z, a4.w};
            float bv[4] = {b4.x, b4.y, b4.z, b4.w};
            #pragma unroll
            for (int r = 0; r < 4; ++r)
                #pragma unroll
                for (int c = 0; c < 4; ++c)
                    acc[r][c] += av[r] * bv[c];
        }
        __syncthreads();
    }

    #pragma unroll
    for (int r = 0; r < 4; ++r) {
        const int trow = row0 + ty * 4 + r;
        #pragma unroll
        for (int c = 0; c < 4; ++c) {
            const int dcol = col0 + tx * 4 + c;
            Out[(size_t)trow * 512 + dcol] = acc[r][c] + bias[dcol];
        }
    }
}

extern "C" void kernel_launch(void* const* d_in, const int* in_sizes, int n_in,
                              void* d_out, int out_size, void* d_ws, size_t ws_size,
                              hipStream_t stream)
{
    const float* q  = (const float*)d_in[0];
    const float* k  = (const float*)d_in[1];
    const float* v  = (const float*)d_in[2];
    const float* w_gq = (const float*)d_in[3];  const float* b_gq = (const float*)d_in[4];
    const float* w_gk = (const float*)d_in[5];  const float* b_gk = (const float*)d_in[6];
    const float* w_gv = (const float*)d_in[7];  const float* b_gv = (const float*)d_in[8];
    const float* w_cq = (const float*)d_in[9];  const float* b_cq = (const float*)d_in[10];
    const float* w_ck = (const float*)d_in[11]; const float* b_ck = (const float*)d_in[12];
    // d_in[13], d_in[14] = w_cv, b_cv : dead code in the reference
    const float* w_mq = (const float*)d_in[15]; const float* b_mq = (const float*)d_in[16];
    const float* w_mk = (const float*)d_in[17]; const float* b_mk = (const float*)d_in[18];
    const float* w_o  = (const float*)d_in[19]; const float* b_o  = (const float*)d_in[20];

    float* ws = (float*)d_ws;
    float* p_gq = ws + (size_t)0 * PROJ_ELEMS;
    float* p_gk = ws + (size_t)1 * PROJ_ELEMS;
    float* p_gv = ws + (size_t)2 * PROJ_ELEMS;
    float* p_lq = ws + (size_t)3 * PROJ_ELEMS;
    float* p_lk = ws + (size_t)4 * PROJ_ELEMS;
    float* p_mq = ws + (size_t)5 * PROJ_ELEMS;
    float* p_mk = ws + (size_t)6 * PROJ_ELEMS;
    float* p_ao = ws + (size_t)7 * PROJ_ELEMS;

    ProjArgs pa;
    pa.src[0] = q; pa.w[0] = w_gq; pa.b[0] = b_gq; pa.dst[0] = p_gq;
    pa.src[1] = k; pa.w[1] = w_gk; pa.b[1] = b_gk; pa.dst[1] = p_gk;
    pa.src[2] = v; pa.w[2] = w_gv; pa.b[2] = b_gv; pa.dst[2] = p_gv;
    pa.src[3] = q; pa.w[3] = w_cq; pa.b[3] = b_cq; pa.dst[3] = p_lq;
    pa.src[4] = k; pa.w[4] = w_ck; pa.b[4] = b_ck; pa.dst[4] = p_lk;
    pa.src[5] = q; pa.w[5] = w_mq; pa.b[5] = b_mq; pa.dst[5] = p_mq;
    pa.src[6] = k; pa.w[6] = w_mk; pa.b[6] = b_mk; pa.dst[6] = p_mk;

    proj_kernel<<<dim3(192, 8, 7), 256, 0, stream>>>(pa);
    attn_kernel<<<dim3(192, 32), 256, 0, stream>>>(p_gq, p_gk, p_gv, p_lq, p_lk,
                                                   p_mq, p_mk, p_ao);
    oproj_kernel<<<dim3(192, 8), 256, 0, stream>>>(p_ao, w_o, b_o, (float*)d_out);
}